// Round 1
// baseline (3117.246 us; speedup 1.0000x reference)
//
#include <hip/hip_runtime.h>
#include <stdint.h>

typedef unsigned int u32;
typedef unsigned long long u64;

// JAX >= 0.4.36 defaults to threefry_partitionable=True. If tokens mismatch
// uniformly, flip this to 0 (legacy concat(y0,y1) counter layout).
#define JAX_PARTITIONABLE 1

#define HD     1024
#define BBATCH 64
#define TSTEP  32
#define VOCAB  32000
#define NSLICE 1000      // VOCAB / 32
#define NROWS  2048      // TSTEP * BBATCH
#define GATE6  6144      // 6 * HD

// ---------------- Threefry-2x32 (matches jax._src.prng) ----------------
__device__ __forceinline__ void threefry2x32(u32 k0, u32 k1, u32 x0, u32 x1,
                                             u32& y0, u32& y1) {
  u32 ks2 = k0 ^ k1 ^ 0x1BD11BDAu;
  x0 += k0; x1 += k1;
#define TFR(r) do { x0 += x1; x1 = (x1 << (r)) | (x1 >> (32 - (r))); x1 ^= x0; } while (0)
  TFR(13); TFR(15); TFR(26); TFR(6);   x0 += k1;  x1 += ks2 + 1u;
  TFR(17); TFR(29); TFR(16); TFR(24);  x0 += ks2; x1 += k0 + 2u;
  TFR(13); TFR(15); TFR(26); TFR(6);   x0 += k0;  x1 += k1 + 3u;
  TFR(17); TFR(29); TFR(16); TFR(24);  x0 += k1;  x1 += ks2 + 4u;
  TFR(13); TFR(15); TFR(26); TFR(6);   x0 += ks2; x1 += k0 + 5u;
#undef TFR
  y0 = x0; y1 = x1;
}

__device__ __forceinline__ u32 jax_random_bits(u32 n) {
#if JAX_PARTITIONABLE
  u32 y0, y1; threefry2x32(0u, 42u, 0u, n, y0, y1);
  return y0 ^ y1;
#else
  u32 y0, y1;
  if (n < 8192u) { threefry2x32(0u, 42u, n, n + 8192u, y0, y1); return y0; }
  else           { threefry2x32(0u, 42u, n - 8192u, n, y0, y1); return y1; }
#endif
}

// value-desc, tie -> lower vocab index wins
__device__ __forceinline__ u64 packkey(float v, int idx) {
  u32 b = __float_as_uint(v);
  b = (b & 0x80000000u) ? ~b : (b | 0x80000000u);
  return ((u64)b << 32) | (u64)(~(u32)idx);
}

// ---------------- skinny NT GEMM: part[s][64][n] = A[64,1024] @ B[n,1024]^T ----
// grid (nblocks, 4 ksplits); block tile 64 rows x 32 cols; K chunk 128.
__global__ __launch_bounds__(256) void gemm64_nt(
    const float* __restrict__ A, const float* __restrict__ Bih,
    const float* __restrict__ Bhh, int colBase, float* __restrict__ part) {
  __shared__ float4 As4[64 * 33];
  __shared__ float4 Bs4[32 * 33];
  const int tid = threadIdx.x;
  const int n0 = colBase + blockIdx.x * 32;
  const float* Brow = (n0 < 3072) ? (Bih + (size_t)n0 * HD)
                                  : (Bhh + (size_t)(n0 - 3072) * HD);
  const int ks = blockIdx.y * 256;
  const int tc = tid & 7, trg = tid >> 3;
  float acc[2][4] = {};
  for (int kc = 0; kc < 2; ++kc) {
    const int k0 = ks + kc * 128;
#pragma unroll
    for (int l = 0; l < 8; ++l) {
      int m = tid + l * 256; int row = m >> 5, k4 = m & 31;
      As4[row * 33 + k4] = *(const float4*)(A + (size_t)row * HD + k0 + k4 * 4);
    }
#pragma unroll
    for (int l = 0; l < 4; ++l) {
      int m = tid + l * 256; int row = m >> 5, k4 = m & 31;
      Bs4[row * 33 + k4] = *(const float4*)(Brow + (size_t)row * HD + k0 + k4 * 4);
    }
    __syncthreads();
#pragma unroll
    for (int kq = 0; kq < 32; ++kq) {
      float4 av[2], bv[4];
      av[0] = As4[trg * 33 + kq];
      av[1] = As4[(trg + 32) * 33 + kq];
      bv[0] = Bs4[tc * 33 + kq];
      bv[1] = Bs4[(tc + 8) * 33 + kq];
      bv[2] = Bs4[(tc + 16) * 33 + kq];
      bv[3] = Bs4[(tc + 24) * 33 + kq];
#pragma unroll
      for (int i = 0; i < 2; ++i)
#pragma unroll
        for (int j = 0; j < 4; ++j) {
          acc[i][j] += av[i].x * bv[j].x;
          acc[i][j] += av[i].y * bv[j].y;
          acc[i][j] += av[i].z * bv[j].z;
          acc[i][j] += av[i].w * bv[j].w;
        }
    }
    __syncthreads();
  }
  float* P = part + (size_t)blockIdx.y * BBATCH * GATE6;
#pragma unroll
  for (int i = 0; i < 2; ++i) {
    int b = trg + 32 * i;
#pragma unroll
    for (int j = 0; j < 4; ++j)
      P[(size_t)b * GATE6 + n0 + tc + 8 * j] = acc[i][j];
  }
}

// ---------------- fc_in combine ----------------
__global__ __launch_bounds__(256) void combine_fcin(
    const float* __restrict__ part, const float* __restrict__ b_fc,
    float* __restrict__ h) {
  int idx = blockIdx.x * 256 + threadIdx.x;  // 0..65535
  int b = idx >> 10, j = idx & 1023;
  const size_t S = (size_t)BBATCH * GATE6;
  const float* p = part + (size_t)b * GATE6;
  float d = p[j]; d += p[S + j]; d += p[2 * S + j]; d += p[3 * S + j];
  h[idx] = d + b_fc[j];
}

// ---------------- GRU gate math ----------------
__global__ __launch_bounds__(256) void gru_gate(
    const float* __restrict__ part, const float* __restrict__ b_ih,
    const float* __restrict__ b_hh, float* __restrict__ h,
    float* __restrict__ outs, int t, int first) {
  int idx = blockIdx.x * 256 + threadIdx.x;  // 0..65535
  int b = idx >> 10, j = idx & 1023;
  const size_t S = (size_t)BBATCH * GATE6;
  const float* p = part + (size_t)b * GATE6;
  float gir, giz, gin;
  if (first) {
    gir = b_ih[j]; giz = b_ih[HD + j]; gin = b_ih[2 * HD + j];
  } else {
    float d0 = p[j];          d0 += p[S + j];          d0 += p[2*S + j];          d0 += p[3*S + j];
    float d1 = p[HD + j];     d1 += p[S + HD + j];     d1 += p[2*S + HD + j];     d1 += p[3*S + HD + j];
    float d2 = p[2*HD + j];   d2 += p[S + 2*HD + j];   d2 += p[2*S + 2*HD + j];   d2 += p[3*S + 2*HD + j];
    gir = d0 + b_ih[j]; giz = d1 + b_ih[HD + j]; gin = d2 + b_ih[2 * HD + j];
  }
  float e0 = p[3072 + j];        e0 += p[S + 3072 + j];        e0 += p[2*S + 3072 + j];        e0 += p[3*S + 3072 + j];
  float e1 = p[3072 + HD + j];   e1 += p[S + 3072 + HD + j];   e1 += p[2*S + 3072 + HD + j];   e1 += p[3*S + 3072 + HD + j];
  float e2 = p[3072 + 2*HD + j]; e2 += p[S + 3072 + 2*HD + j]; e2 += p[2*S + 3072 + 2*HD + j]; e2 += p[3*S + 3072 + 2*HD + j];
  float ghr = e0 + b_hh[j];
  float ghz = e1 + b_hh[HD + j];
  float ghn = e2 + b_hh[2 * HD + j];
  float r = 1.0f / (1.0f + expf(-(gir + ghr)));
  float z = 1.0f / (1.0f + expf(-(giz + ghz)));
  float n = tanhf(gin + r * ghn);
  float hp = h[idx];
  float hn = (1.0f - z) * n + z * hp;
  h[idx] = hn;
  outs[((size_t)t * BBATCH + b) * HD + j] = hn;
}

// ---------------- fc_out GEMM with fused per-slice selection ----------------
// grid (NSLICE, 16); block tile 128 rows x 32 vocab cols; K chunk 64.
__global__ __launch_bounds__(256) void gemm_out(
    const float* __restrict__ A, const float* __restrict__ W,
    const float* __restrict__ b_out, float* __restrict__ smax,
    float* __restrict__ ssum, u64* __restrict__ keys) {
  __shared__ float4 As4[128 * 17];
  __shared__ float4 Bs4[32 * 17];
  const int tid = threadIdx.x;
  const int slice = blockIdx.x;
  const int n0 = slice * 32;
  const int r0 = blockIdx.y * 128;
  const int tc = tid & 7, trg = tid >> 3;
  float acc[4][4] = {};
  for (int kc = 0; kc < 16; ++kc) {
    const int k0 = kc * 64;
#pragma unroll
    for (int l = 0; l < 8; ++l) {
      int m = tid + l * 256; int row = m >> 4, k4 = m & 15;
      As4[row * 17 + k4] = *(const float4*)(A + (size_t)(r0 + row) * HD + k0 + k4 * 4);
    }
#pragma unroll
    for (int l = 0; l < 2; ++l) {
      int m = tid + l * 256; int row = m >> 4, k4 = m & 15;
      Bs4[row * 17 + k4] = *(const float4*)(W + (size_t)(n0 + row) * HD + k0 + k4 * 4);
    }
    __syncthreads();
#pragma unroll
    for (int kq = 0; kq < 16; ++kq) {
      float4 av[4], bv[4];
      av[0] = As4[trg * 17 + kq];
      av[1] = As4[(trg + 32) * 17 + kq];
      av[2] = As4[(trg + 64) * 17 + kq];
      av[3] = As4[(trg + 96) * 17 + kq];
      bv[0] = Bs4[tc * 17 + kq];
      bv[1] = Bs4[(tc + 8) * 17 + kq];
      bv[2] = Bs4[(tc + 16) * 17 + kq];
      bv[3] = Bs4[(tc + 24) * 17 + kq];
#pragma unroll
      for (int i = 0; i < 4; ++i)
#pragma unroll
        for (int j = 0; j < 4; ++j) {
          acc[i][j] += av[i].x * bv[j].x;
          acc[i][j] += av[i].y * bv[j].y;
          acc[i][j] += av[i].z * bv[j].z;
          acc[i][j] += av[i].w * bv[j].w;
        }
    }
    __syncthreads();
  }
  // epilogue: logits -> LDS, per-row max / sumexp / top-4 keys per slice
  float bo[4];
#pragma unroll
  for (int j = 0; j < 4; ++j) bo[j] = b_out[n0 + tc + 8 * j];
  float* Cs = (float*)As4;  // [128][33]
#pragma unroll
  for (int i = 0; i < 4; ++i)
#pragma unroll
    for (int j = 0; j < 4; ++j)
      Cs[(trg + 32 * i) * 33 + (tc + 8 * j)] = acc[i][j] + bo[j];
  __syncthreads();
  if (tid < 128) {
    const float* row = Cs + tid * 33;
    float mx = row[0];
#pragma unroll
    for (int c = 1; c < 32; ++c) mx = fmaxf(mx, row[c]);
    float sm = 0.0f;
    for (int c = 0; c < 32; ++c) sm += expf(row[c] - mx);
    u64 t4[4] = {0, 0, 0, 0};
    for (int c = 0; c < 32; ++c) {
      u64 k = packkey(row[c], n0 + c);
      if (k > t4[3]) {
        t4[3] = k;
        if (t4[3] > t4[2]) { u64 tm = t4[2]; t4[2] = t4[3]; t4[3] = tm; }
        if (t4[2] > t4[1]) { u64 tm = t4[1]; t4[1] = t4[2]; t4[2] = tm; }
        if (t4[1] > t4[0]) { u64 tm = t4[0]; t4[0] = t4[1]; t4[1] = tm; }
      }
    }
    int gr = r0 + tid;
    size_t o = (size_t)gr * NSLICE + slice;
    smax[o] = mx;
    ssum[o] = sm;
    u64* kp = keys + o * 4;
    kp[0] = t4[0]; kp[1] = t4[1]; kp[2] = t4[2]; kp[3] = t4[3];
  }
}

// ---------------- per-row merge: LSE, exact top-8, Gumbel sample ----------------
__global__ __launch_bounds__(256) void merge_sample(
    const float* __restrict__ smax, const float* __restrict__ ssum,
    const u64* __restrict__ keys, int* __restrict__ out) {
  const int r = blockIdx.x, tid = threadIdx.x;
  __shared__ float red[256];
  __shared__ u64 K[4000];
  __shared__ u64 redk[256];
  __shared__ u64 top[8];
  const float* SM = smax + (size_t)r * NSLICE;
  const float* SS = ssum + (size_t)r * NSLICE;
  // global row max
  float m = -3.4e38f;
  for (int s = tid; s < NSLICE; s += 256) m = fmaxf(m, SM[s]);
  red[tid] = m; __syncthreads();
  for (int o = 128; o; o >>= 1) {
    if (tid < o) red[tid] = fmaxf(red[tid], red[tid + o]);
    __syncthreads();
  }
  const float M = red[0];
  __syncthreads();
  // deterministic sum of exp
  float p = 0.0f;
  for (int s = tid; s < NSLICE; s += 256) p += SS[s] * expf(SM[s] - M);
  red[tid] = p; __syncthreads();
  for (int o = 128; o; o >>= 1) {
    if (tid < o) red[tid] += red[tid + o];
    __syncthreads();
  }
  const float logSig = logf(red[0]);
  // load candidate keys
  for (int i = tid; i < 4000; i += 256) K[i] = keys[(size_t)r * 4000 + i];
  __syncthreads();
  // 8 rounds of argmax
  for (int it = 0; it < 8; ++it) {
    u64 b = 0;
    for (int i = tid; i < 4000; i += 256) b = (K[i] > b) ? K[i] : b;
    redk[tid] = b; __syncthreads();
    for (int o = 128; o; o >>= 1) {
      if (tid < o) redk[tid] = (redk[tid] > redk[tid + o]) ? redk[tid] : redk[tid + o];
      __syncthreads();
    }
    u64 w = redk[0];
    if (tid == 0) top[it] = w;
    __syncthreads();
    for (int i = tid; i < 4000; i += 256) if (K[i] == w) K[i] = 0;
    __syncthreads();
  }
  if (tid == 0) {
    float lp[8]; int vi[8];
    for (int q = 0; q < 8; ++q) {
      u64 w = top[q];
      u32 ub = (u32)(w >> 32);
      float v = __uint_as_float((ub & 0x80000000u) ? (ub ^ 0x80000000u) : ~ub);
      vi[q] = (int)(~(u32)(w & 0xffffffffu));
      lp[q] = (v - M) - logSig;  // log_softmax form: shifted - log(sum(exp(shifted)))
    }
    // sort by (logp desc, idx asc) — matches lax.top_k tie rule on logp
    for (int a = 0; a < 8; ++a)
      for (int b2 = a + 1; b2 < 8; ++b2) {
        bool sw = (lp[b2] > lp[a]) || (lp[b2] == lp[a] && vi[b2] < vi[a]);
        if (sw) {
          float tf = lp[a]; lp[a] = lp[b2]; lp[b2] = tf;
          int ti = vi[a]; vi[a] = vi[b2]; vi[b2] = ti;
        }
      }
    // gumbel-max sampling, first-max-wins ties (jnp.argmax)
    const float TINY = 1.17549435e-38f;
    float best = -3.4e38f; int bi = 0;
    for (int k = 0; k < 8; ++k) {
      u32 n = (u32)(r * 8 + k);
      u32 bits = jax_random_bits(n);
      float f = __uint_as_float((bits >> 9) | 0x3f800000u) - 1.0f;
      float u = f * (1.0f - TINY) + TINY;
      u = fmaxf(TINY, u);
      float g = -logf(-logf(u));
      float s = g + lp[k];
      if (s > best) { best = s; bi = k; }
    }
    int t = r >> 6, b = r & 63;
    out[b * TSTEP + t] = vi[bi];
  }
}

extern "C" void kernel_launch(void* const* d_in, const int* in_sizes, int n_in,
                              void* d_out, int out_size, void* d_ws, size_t ws_size,
                              hipStream_t stream) {
  (void)in_sizes; (void)n_in; (void)out_size; (void)ws_size;
  const float* vectors = (const float*)d_in[0];
  const float* W_fc_in = (const float*)d_in[1];
  const float* b_fc_in = (const float*)d_in[2];
  const float* W_ih    = (const float*)d_in[3];
  const float* W_hh    = (const float*)d_in[4];
  const float* b_ih    = (const float*)d_in[5];
  const float* b_hh    = (const float*)d_in[6];
  const float* W_out   = (const float*)d_in[7];
  const float* b_out   = (const float*)d_in[8];
  int* out = (int*)d_out;

  float* ws = (float*)d_ws;
  float* h    = ws;                                  // 64*1024
  float* outs = h + (size_t)BBATCH * HD;             // 2048*1024
  float* part = outs + (size_t)NROWS * HD;           // 4*64*6144
  float* smax = part + (size_t)4 * BBATCH * GATE6;   // 2048*1000
  float* ssum = smax + (size_t)NROWS * NSLICE;       // 2048*1000
  u64*   keys = (u64*)(ssum + (size_t)NROWS * NSLICE); // 2048*1000*4 u64

  // fc_in: h0 = vectors @ W_fc_in^T + b_fc_in
  gemm64_nt<<<dim3(32, 4), 256, 0, stream>>>(vectors, W_fc_in, W_fc_in, 0, part);
  combine_fcin<<<256, 256, 0, stream>>>(part, b_fc_in, h);

  // 32 GRU steps (x == h for t >= 1; t == 0 uses x = 0 -> gi = b_ih)
  for (int t = 0; t < TSTEP; ++t) {
    if (t == 0)
      gemm64_nt<<<dim3(96, 4), 256, 0, stream>>>(h, W_ih, W_hh, 3072, part);
    else
      gemm64_nt<<<dim3(192, 4), 256, 0, stream>>>(h, W_ih, W_hh, 0, part);
    gru_gate<<<256, 256, 0, stream>>>(part, b_ih, b_hh, h, outs, t, t == 0 ? 1 : 0);
  }

  // fc_out + fused per-slice selection
  gemm_out<<<dim3(NSLICE, 16), 256, 0, stream>>>(outs, W_out, b_out, smax, ssum, keys);

  // per-row LSE + exact top-8 + Threefry/Gumbel sampling
  merge_sample<<<NROWS, 256, 0, stream>>>(smax, ssum, keys, out);
}

// Round 2
// 1540.306 us; speedup vs baseline: 2.0238x; 2.0238x over previous
//
#include <hip/hip_runtime.h>
#include <stdint.h>

typedef unsigned int u32;
typedef unsigned long long u64;
typedef __attribute__((ext_vector_type(8))) short bf16x8;
typedef __attribute__((ext_vector_type(4))) float f32x4;

#define JAX_PARTITIONABLE 1

#define HD     1024
#define BBATCH 64
#define TSTEP  32
#define VOCAB  32000
#define NROWS  2048      // TSTEP * BBATCH
#define GATE6  6144      // 6 * HD
#define NCB    250       // 32000 / 128 col-blocks
#define NCAND  16

// ---------------- Threefry-2x32 (matches jax._src.prng) ----------------
__device__ __forceinline__ void threefry2x32(u32 k0, u32 k1, u32 x0, u32 x1,
                                             u32& y0, u32& y1) {
  u32 ks2 = k0 ^ k1 ^ 0x1BD11BDAu;
  x0 += k0; x1 += k1;
#define TFR(r) do { x0 += x1; x1 = (x1 << (r)) | (x1 >> (32 - (r))); x1 ^= x0; } while (0)
  TFR(13); TFR(15); TFR(26); TFR(6);   x0 += k1;  x1 += ks2 + 1u;
  TFR(17); TFR(29); TFR(16); TFR(24);  x0 += ks2; x1 += k0 + 2u;
  TFR(13); TFR(15); TFR(26); TFR(6);   x0 += k0;  x1 += k1 + 3u;
  TFR(17); TFR(29); TFR(16); TFR(24);  x0 += k1;  x1 += ks2 + 4u;
  TFR(13); TFR(15); TFR(26); TFR(6);   x0 += ks2; x1 += k0 + 5u;
#undef TFR
  y0 = x0; y1 = x1;
}

__device__ __forceinline__ u32 jax_random_bits(u32 n) {
#if JAX_PARTITIONABLE
  u32 y0, y1; threefry2x32(0u, 42u, 0u, n, y0, y1);
  return y0 ^ y1;
#else
  u32 y0, y1;
  if (n < 8192u) { threefry2x32(0u, 42u, n, n + 8192u, y0, y1); return y0; }
  else           { threefry2x32(0u, 42u, n - 8192u, n, y0, y1); return y1; }
#endif
}

// value-desc, tie -> lower vocab index wins
__device__ __forceinline__ u64 packkey(float v, int idx) {
  u32 b = __float_as_uint(v);
  b = (b & 0x80000000u) ? ~b : (b | 0x80000000u);
  return ((u64)b << 32) | (u64)(~(u32)idx);
}

__device__ __forceinline__ void insert4(u64* t4, u64 k) {
  if (k > t4[3]) {
    t4[3] = k;
    if (t4[3] > t4[2]) { u64 tm = t4[2]; t4[2] = t4[3]; t4[3] = tm; }
    if (t4[2] > t4[1]) { u64 tm = t4[1]; t4[1] = t4[2]; t4[2] = tm; }
    if (t4[1] > t4[0]) { u64 tm = t4[0]; t4[0] = t4[1]; t4[1] = tm; }
  }
}

__device__ __forceinline__ unsigned short f2bf_rne(float x) {
  u32 u = __float_as_uint(x);
  return (unsigned short)((u + 0x7fffu + ((u >> 16) & 1u)) >> 16);
}

typedef const __attribute__((address_space(1))) void* gas_ptr;
typedef __attribute__((address_space(3))) void* las_ptr;
__device__ __forceinline__ void gload16(const void* g, void* l) {
  __builtin_amdgcn_global_load_lds((gas_ptr)g, (las_ptr)l, 16, 0, 0);
}

// ---------------- fp32 -> bf16 bulk convert (8 elems / thread / iter) -----
__global__ __launch_bounds__(256) void tobf16(const float* __restrict__ src,
                                              unsigned short* __restrict__ dst,
                                              int n8) {
  int i = blockIdx.x * 256 + threadIdx.x;
  const int stride = gridDim.x * 256;
  for (; i < n8; i += stride) {
    const float4* s4 = (const float4*)src + (size_t)i * 2;
    float4 a = s4[0], b = s4[1];
    u32 o0 = f2bf_rne(a.x) | ((u32)f2bf_rne(a.y) << 16);
    u32 o1 = f2bf_rne(a.z) | ((u32)f2bf_rne(a.w) << 16);
    u32 o2 = f2bf_rne(b.x) | ((u32)f2bf_rne(b.y) << 16);
    u32 o3 = f2bf_rne(b.z) | ((u32)f2bf_rne(b.w) << 16);
    ((uint4*)dst)[i] = make_uint4(o0, o1, o2, o3);
  }
}

// ---------------- skinny NT GEMM: part[s][64][n] = A[64,1024] @ B[n,1024]^T ----
__global__ __launch_bounds__(256) void gemm64_nt(
    const float* __restrict__ A, const float* __restrict__ Bih,
    const float* __restrict__ Bhh, int colBase, float* __restrict__ part) {
  __shared__ float4 As4[64 * 33];
  __shared__ float4 Bs4[32 * 33];
  const int tid = threadIdx.x;
  const int n0 = colBase + blockIdx.x * 32;
  const float* Brow = (n0 < 3072) ? (Bih + (size_t)n0 * HD)
                                  : (Bhh + (size_t)(n0 - 3072) * HD);
  const int ks = blockIdx.y * 256;
  const int tc = tid & 7, trg = tid >> 3;
  float acc[2][4] = {};
  for (int kc = 0; kc < 2; ++kc) {
    const int k0 = ks + kc * 128;
#pragma unroll
    for (int l = 0; l < 8; ++l) {
      int m = tid + l * 256; int row = m >> 5, k4 = m & 31;
      As4[row * 33 + k4] = *(const float4*)(A + (size_t)row * HD + k0 + k4 * 4);
    }
#pragma unroll
    for (int l = 0; l < 4; ++l) {
      int m = tid + l * 256; int row = m >> 5, k4 = m & 31;
      Bs4[row * 33 + k4] = *(const float4*)(Brow + (size_t)row * HD + k0 + k4 * 4);
    }
    __syncthreads();
#pragma unroll
    for (int kq = 0; kq < 32; ++kq) {
      float4 av[2], bv[4];
      av[0] = As4[trg * 33 + kq];
      av[1] = As4[(trg + 32) * 33 + kq];
      bv[0] = Bs4[tc * 33 + kq];
      bv[1] = Bs4[(tc + 8) * 33 + kq];
      bv[2] = Bs4[(tc + 16) * 33 + kq];
      bv[3] = Bs4[(tc + 24) * 33 + kq];
#pragma unroll
      for (int i = 0; i < 2; ++i)
#pragma unroll
        for (int j = 0; j < 4; ++j) {
          acc[i][j] += av[i].x * bv[j].x;
          acc[i][j] += av[i].y * bv[j].y;
          acc[i][j] += av[i].z * bv[j].z;
          acc[i][j] += av[i].w * bv[j].w;
        }
    }
    __syncthreads();
  }
  float* P = part + (size_t)blockIdx.y * BBATCH * GATE6;
#pragma unroll
  for (int i = 0; i < 2; ++i) {
    int b = trg + 32 * i;
#pragma unroll
    for (int j = 0; j < 4; ++j)
      P[(size_t)b * GATE6 + n0 + tc + 8 * j] = acc[i][j];
  }
}

// ---------------- fc_in combine ----------------
__global__ __launch_bounds__(256) void combine_fcin(
    const float* __restrict__ part, const float* __restrict__ b_fc,
    float* __restrict__ h) {
  int idx = blockIdx.x * 256 + threadIdx.x;
  int j = idx & 1023; int b = idx >> 10;
  const size_t S = (size_t)BBATCH * GATE6;
  const float* p = part + (size_t)b * GATE6;
  float d = p[j]; d += p[S + j]; d += p[2 * S + j]; d += p[3 * S + j];
  h[idx] = d + b_fc[j];
}

// ---------------- GRU gate math (also emits bf16 copy of outs) -----------
__global__ __launch_bounds__(256) void gru_gate(
    const float* __restrict__ part, const float* __restrict__ b_ih,
    const float* __restrict__ b_hh, float* __restrict__ h,
    float* __restrict__ outs, unsigned short* __restrict__ outs_bf,
    int t, int first) {
  int idx = blockIdx.x * 256 + threadIdx.x;
  int b = idx >> 10, j = idx & 1023;
  const size_t S = (size_t)BBATCH * GATE6;
  const float* p = part + (size_t)b * GATE6;
  float gir, giz, gin;
  if (first) {
    gir = b_ih[j]; giz = b_ih[HD + j]; gin = b_ih[2 * HD + j];
  } else {
    float d0 = p[j];        d0 += p[S + j];        d0 += p[2*S + j];        d0 += p[3*S + j];
    float d1 = p[HD + j];   d1 += p[S + HD + j];   d1 += p[2*S + HD + j];   d1 += p[3*S + HD + j];
    float d2 = p[2*HD + j]; d2 += p[S + 2*HD + j]; d2 += p[2*S + 2*HD + j]; d2 += p[3*S + 2*HD + j];
    gir = d0 + b_ih[j]; giz = d1 + b_ih[HD + j]; gin = d2 + b_ih[2 * HD + j];
  }
  float e0 = p[3072 + j];        e0 += p[S + 3072 + j];        e0 += p[2*S + 3072 + j];        e0 += p[3*S + 3072 + j];
  float e1 = p[3072 + HD + j];   e1 += p[S + 3072 + HD + j];   e1 += p[2*S + 3072 + HD + j];   e1 += p[3*S + 3072 + HD + j];
  float e2 = p[3072 + 2*HD + j]; e2 += p[S + 3072 + 2*HD + j]; e2 += p[2*S + 3072 + 2*HD + j]; e2 += p[3*S + 3072 + 2*HD + j];
  float ghr = e0 + b_hh[j];
  float ghz = e1 + b_hh[HD + j];
  float ghn = e2 + b_hh[2 * HD + j];
  float r = 1.0f / (1.0f + expf(-(gir + ghr)));
  float z = 1.0f / (1.0f + expf(-(giz + ghz)));
  float n = tanhf(gin + r * ghn);
  float hp = h[idx];
  float hn = (1.0f - z) * n + z * hp;
  h[idx] = hn;
  size_t o = ((size_t)t * BBATCH + b) * HD + j;
  outs[o] = hn;
  outs_bf[o] = f2bf_rne(hn);
}

// ---------------- bf16 MFMA fc_out with fused top-4/128-col prefilter -----
// grid (NCB=250 colblocks, 16 rowblocks); 256 threads (4 waves, 2x2).
// C[128,128] tile of logits = A[128,1024]_bf16 @ W[128,1024]_bf16^T + b_out.
__global__ __launch_bounds__(256) void gemm_out_mfma(
    const unsigned short* __restrict__ Abf, const unsigned short* __restrict__ Bbf,
    const float* __restrict__ b_out, u64* __restrict__ keys) {
  __shared__ unsigned short Asm[128 * 64];   // 16 KB, xor-swizzled granules
  __shared__ unsigned short Bsm[128 * 64];   // 16 KB
  __shared__ float Cs[32 * 133];             // 17 KB epilogue quarter
  __shared__ u64 pk[64 * 4];                 // 2 KB partial top-4 keys

  const int tid = threadIdx.x;
  const int lane = tid & 63;
  const int wid = tid >> 6;
  const int wr = wid >> 1, wc = wid & 1;
  const int cb = blockIdx.x;
  const int r0 = blockIdx.y * 128;
  const int n0 = cb * 128;

  const unsigned short* Ag = Abf + (size_t)r0 * HD;
  const unsigned short* Bg = Bbf + (size_t)n0 * HD;

  // staging geometry: chunk = 8 rows x 64 k (1 KB); lane l -> row chunk*8 + (l>>3),
  // source granule (16B = 8 bf16) index = (l&7) ^ (l>>3)   [xor pre-swizzle]
  const int rc = lane >> 3;
  const int gr8 = ((lane & 7) ^ rc) * 8;

  f32x4 acc[4][4];
#pragma unroll
  for (int m = 0; m < 4; ++m)
#pragma unroll
    for (int n = 0; n < 4; ++n) acc[m][n] = (f32x4){0.f, 0.f, 0.f, 0.f};

  const int l15 = lane & 15;
  const int kseg = (lane >> 4) * 16;         // byte offset of lane's 8-bf16 seg
  for (int kt = 0; kt < 16; ++kt) {
    const int k0 = kt * 64;
#pragma unroll
    for (int c = 0; c < 4; ++c) {
      int ch = wid * 4 + c;
      int row = ch * 8 + rc;
      gload16(Ag + (size_t)row * HD + k0 + gr8, Asm + ch * 512);
      gload16(Bg + (size_t)row * HD + k0 + gr8, Bsm + ch * 512);
    }
    asm volatile("s_waitcnt vmcnt(0)" ::: "memory");
    __syncthreads();
#pragma unroll
    for (int ks = 0; ks < 2; ++ks) {
      bf16x8 a[4], b[4];
#pragma unroll
      for (int m = 0; m < 4; ++m) {
        int row = wr * 64 + m * 16 + l15;
        int kb = ks * 64 + kseg;
        int off = row * 128 + (kb ^ ((row & 7) << 4));
        a[m] = *(const bf16x8*)((const char*)Asm + off);
      }
#pragma unroll
      for (int n = 0; n < 4; ++n) {
        int row = wc * 64 + n * 16 + l15;
        int kb = ks * 64 + kseg;
        int off = row * 128 + (kb ^ ((row & 7) << 4));
        b[n] = *(const bf16x8*)((const char*)Bsm + off);
      }
#pragma unroll
      for (int m = 0; m < 4; ++m)
#pragma unroll
        for (int n = 0; n < 4; ++n)
          acc[m][n] = __builtin_amdgcn_mfma_f32_16x16x32_bf16(a[m], b[n], acc[m][n], 0, 0, 0);
    }
    __syncthreads();
  }

  // epilogue: 4 quarters of 32 rows; per row top-4 keys over 128 cols
  float bo[4];
#pragma unroll
  for (int n = 0; n < 4; ++n) bo[n] = b_out[n0 + wc * 64 + n * 16 + l15];

  for (int q = 0; q < 4; ++q) {
    if (wr == (q >> 1)) {
      int mbase = (q & 1) * 2;
#pragma unroll
      for (int mi = 0; mi < 2; ++mi) {
        int m = mbase + mi;
#pragma unroll
        for (int n = 0; n < 4; ++n) {
          int c = wc * 64 + n * 16 + l15;
#pragma unroll
          for (int j = 0; j < 4; ++j) {
            int lr = mi * 16 + (lane >> 4) * 4 + j;
            Cs[lr * 133 + c] = acc[m][n][j] + bo[n];
          }
        }
      }
    }
    __syncthreads();
    if (tid < 64) {
      int rr = tid >> 1, hc = (tid & 1) * 64;
      const float* rp = Cs + rr * 133 + hc;
      u64 t4[4] = {0, 0, 0, 0};
      for (int c = 0; c < 64; ++c) insert4(t4, packkey(rp[c], n0 + hc + c));
      u64* d = pk + tid * 4;
      d[0] = t4[0]; d[1] = t4[1]; d[2] = t4[2]; d[3] = t4[3];
    }
    __syncthreads();
    if (tid < 32) {
      const u64* a4 = pk + tid * 8;
      u64 t4[4] = {a4[0], a4[1], a4[2], a4[3]};
      insert4(t4, a4[4]); insert4(t4, a4[5]); insert4(t4, a4[6]); insert4(t4, a4[7]);
      int grow = r0 + q * 32 + tid;
      u64* kp = keys + ((size_t)grow * NCB + cb) * 4;
      kp[0] = t4[0]; kp[1] = t4[1]; kp[2] = t4[2]; kp[3] = t4[3];
    }
    __syncthreads();
  }
}

// ---------------- per-row: top-16 candidates -> fp32 rescore -> top-8 -> sample --
__global__ __launch_bounds__(256) void merge_sample2(
    const u64* __restrict__ keys, const float* __restrict__ outs,
    const float* __restrict__ W_out, const float* __restrict__ b_out,
    int* __restrict__ out) {
  const int r = blockIdx.x, tid = threadIdx.x;
  __shared__ u64 K[1000];
  __shared__ u64 redk[256];
  __shared__ u64 topw[NCAND];
  __shared__ float candv[NCAND];
  __shared__ float row_f[1024];
  for (int i = tid; i < 1000; i += 256) K[i] = keys[(size_t)r * 1000 + i];
  for (int i = tid; i < 1024; i += 256) row_f[i] = outs[(size_t)r * 1024 + i];
  __syncthreads();
  // NCAND rounds of argmax-and-kill over 1000 keys
  for (int it = 0; it < NCAND; ++it) {
    u64 b = 0;
#pragma unroll
    for (int l = 0; l < 4; ++l) {
      int i = tid + l * 256;
      if (i < 1000) { u64 v = K[i]; b = (v > b) ? v : b; }
    }
    redk[tid] = b; __syncthreads();
    for (int o = 128; o; o >>= 1) {
      if (tid < o) redk[tid] = (redk[tid] > redk[tid + o]) ? redk[tid] : redk[tid + o];
      __syncthreads();
    }
    u64 w = redk[0];
    if (tid == 0) topw[it] = w;
#pragma unroll
    for (int l = 0; l < 4; ++l) {
      int i = tid + l * 256;
      if (i < 1000 && K[i] == w) K[i] = 0;
    }
    __syncthreads();
  }
  // exact fp32 rescore: 16 cands x 16 threads
  {
    int c = tid >> 4, l16 = tid & 15;
    int vidx = (int)(~(u32)(topw[c] & 0xffffffffu));
    const float* wrow = W_out + (size_t)vidx * HD;
    float s = 0.f;
    for (int e = l16; e < 1024; e += 16) s += row_f[e] * wrow[e];
#pragma unroll
    for (int o = 8; o; o >>= 1) s += __shfl_xor(s, o, 16);
    if (l16 == 0) candv[c] = s + b_out[vidx];
  }
  __syncthreads();
  if (tid == 0) {
    float v[NCAND]; int vi[NCAND];
#pragma unroll
    for (int q = 0; q < NCAND; ++q) {
      v[q] = candv[q];
      vi[q] = (int)(~(u32)(topw[q] & 0xffffffffu));
    }
    // sort by (value desc, idx asc)
    for (int a = 0; a < 8; ++a)
      for (int b2 = a + 1; b2 < NCAND; ++b2) {
        bool sw = (v[b2] > v[a]) || (v[b2] == v[a] && vi[b2] < vi[a]);
        if (sw) {
          float tf = v[a]; v[a] = v[b2]; v[b2] = tf;
          int ti = vi[a]; vi[a] = vi[b2]; vi[b2] = ti;
        }
      }
    const float M = v[0];
    const float TINY = 1.17549435e-38f;
    float best = -3.4e38f; int bi = 0;
    for (int k = 0; k < 8; ++k) {
      float lp = v[k] - M;   // log_softmax shift cancels in gumbel argmax
      u32 bits = jax_random_bits((u32)(r * 8 + k));
      float f = __uint_as_float((bits >> 9) | 0x3f800000u) - 1.0f;
      float u = f * (1.0f - TINY) + TINY;
      u = fmaxf(TINY, u);
      float g = -logf(-logf(u));
      float s = g + lp;
      if (s > best) { best = s; bi = k; }
    }
    int t = r >> 6, b = r & 63;
    out[b * TSTEP + t] = vi[bi];
  }
}

extern "C" void kernel_launch(void* const* d_in, const int* in_sizes, int n_in,
                              void* d_out, int out_size, void* d_ws, size_t ws_size,
                              hipStream_t stream) {
  (void)in_sizes; (void)n_in; (void)out_size; (void)ws_size;
  const float* vectors = (const float*)d_in[0];
  const float* W_fc_in = (const float*)d_in[1];
  const float* b_fc_in = (const float*)d_in[2];
  const float* W_ih    = (const float*)d_in[3];
  const float* W_hh    = (const float*)d_in[4];
  const float* b_ih    = (const float*)d_in[5];
  const float* b_hh    = (const float*)d_in[6];
  const float* W_out   = (const float*)d_in[7];
  const float* b_out   = (const float*)d_in[8];
  int* out = (int*)d_out;

  char* w = (char*)d_ws;
  float* h = (float*)w;                       w += (size_t)BBATCH * HD * 4;         // 256 KB
  float* outs = (float*)w;                    w += (size_t)NROWS * HD * 4;          // 8 MB
  unsigned short* outs_bf = (unsigned short*)w; w += (size_t)NROWS * HD * 2;        // 4 MB
  unsigned short* Wbf = (unsigned short*)w;   w += (size_t)VOCAB * HD * 2;          // 65.5 MB
  float* part = (float*)w;                    w += (size_t)4 * BBATCH * GATE6 * 4;  // 6 MB
  u64* keys = (u64*)w;                        /* 2048*250*4*8 = 16.4 MB */

  // W_out fp32 -> bf16 (prefilter operand)
  tobf16<<<4096, 256, 0, stream>>>(W_out, Wbf, VOCAB * HD / 8);

  // fc_in: h0 = vectors @ W_fc_in^T + b_fc_in
  gemm64_nt<<<dim3(32, 4), 256, 0, stream>>>(vectors, W_fc_in, W_fc_in, 0, part);
  combine_fcin<<<256, 256, 0, stream>>>(part, b_fc_in, h);

  // 32 GRU steps (x == h for t >= 1; t == 0 uses x = 0 -> gi = b_ih)
  for (int t = 0; t < TSTEP; ++t) {
    if (t == 0)
      gemm64_nt<<<dim3(96, 4), 256, 0, stream>>>(h, W_ih, W_hh, 3072, part);
    else
      gemm64_nt<<<dim3(192, 4), 256, 0, stream>>>(h, W_ih, W_hh, 0, part);
    gru_gate<<<256, 256, 0, stream>>>(part, b_ih, b_hh, h, outs, outs_bf, t, t == 0 ? 1 : 0);
  }

  // bf16 MFMA prefilter over the vocab
  gemm_out_mfma<<<dim3(NCB, 16), 256, 0, stream>>>(outs_bf, Wbf, b_out, keys);

  // exact fp32 rescore of top-16 + Threefry/Gumbel sampling
  merge_sample2<<<NROWS, 256, 0, stream>>>(keys, outs, W_out, b_out, out);
}

// Round 4
// 1256.647 us; speedup vs baseline: 2.4806x; 1.2257x over previous
//
#include <hip/hip_runtime.h>
#include <stdint.h>

typedef unsigned int u32;
typedef unsigned long long u64;
typedef unsigned short ushort;
typedef __attribute__((ext_vector_type(8))) short bf16x8;
typedef __attribute__((ext_vector_type(4))) float f32x4;

#define JAX_PARTITIONABLE 1

#define HD     1024
#define BBATCH 64
#define TSTEP  32
#define VOCAB  32000
#define NROWS  2048      // TSTEP * BBATCH
#define GATE6  6144      // 6 * HD
#define NCB    250       // 32000 / 128 col-blocks
#define NCAND  16

// ---------------- Threefry-2x32 (matches jax._src.prng) ----------------
__device__ __forceinline__ void threefry2x32(u32 k0, u32 k1, u32 x0, u32 x1,
                                             u32& y0, u32& y1) {
  u32 ks2 = k0 ^ k1 ^ 0x1BD11BDAu;
  x0 += k0; x1 += k1;
#define TFR(r) do { x0 += x1; x1 = (x1 << (r)) | (x1 >> (32 - (r))); x1 ^= x0; } while (0)
  TFR(13); TFR(15); TFR(26); TFR(6);   x0 += k1;  x1 += ks2 + 1u;
  TFR(17); TFR(29); TFR(16); TFR(24);  x0 += ks2; x1 += k0 + 2u;
  TFR(13); TFR(15); TFR(26); TFR(6);   x0 += k0;  x1 += k1 + 3u;
  TFR(17); TFR(29); TFR(16); TFR(24);  x0 += k1;  x1 += ks2 + 4u;
  TFR(13); TFR(15); TFR(26); TFR(6);   x0 += ks2; x1 += k0 + 5u;
#undef TFR
  y0 = x0; y1 = x1;
}

__device__ __forceinline__ u32 jax_random_bits(u32 n) {
#if JAX_PARTITIONABLE
  u32 y0, y1; threefry2x32(0u, 42u, 0u, n, y0, y1);
  return y0 ^ y1;
#else
  u32 y0, y1;
  if (n < 8192u) { threefry2x32(0u, 42u, n, n + 8192u, y0, y1); return y0; }
  else           { threefry2x32(0u, 42u, n - 8192u, n, y0, y1); return y1; }
#endif
}

// value-desc, tie -> lower vocab index wins
__device__ __forceinline__ u64 packkey(float v, int idx) {
  u32 b = __float_as_uint(v);
  b = (b & 0x80000000u) ? ~b : (b | 0x80000000u);
  return ((u64)b << 32) | (u64)(~(u32)idx);
}

__device__ __forceinline__ void insert4(u64* t4, u64 k) {
  if (k > t4[3]) {
    t4[3] = k;
    if (t4[3] > t4[2]) { u64 tm = t4[2]; t4[2] = t4[3]; t4[3] = tm; }
    if (t4[2] > t4[1]) { u64 tm = t4[1]; t4[1] = t4[2]; t4[2] = tm; }
    if (t4[1] > t4[0]) { u64 tm = t4[0]; t4[0] = t4[1]; t4[1] = tm; }
  }
}

__device__ __forceinline__ ushort f2bf_rne(float x) {
  u32 u = __float_as_uint(x);
  return (ushort)((u + 0x7fffu + ((u >> 16) & 1u)) >> 16);
}
__device__ __forceinline__ float bf2f(ushort h) {
  return __uint_as_float(((u32)h) << 16);
}

typedef const __attribute__((address_space(1))) void* gas_ptr;
typedef __attribute__((address_space(3))) void* las_ptr;
__device__ __forceinline__ void gload16(const void* g, void* l) {
  __builtin_amdgcn_global_load_lds((gas_ptr)g, (las_ptr)l, 16, 0, 0);
}

// ---------------- fp32 -> bf16 bulk convert ----------------
__global__ __launch_bounds__(256) void tobf16(const float* __restrict__ src,
                                              ushort* __restrict__ dst, int n8) {
  int i = blockIdx.x * 256 + threadIdx.x;
  const int stride = gridDim.x * 256;
  for (; i < n8; i += stride) {
    const float4* s4 = (const float4*)src + (size_t)i * 2;
    float4 a = s4[0], b = s4[1];
    u32 o0 = f2bf_rne(a.x) | ((u32)f2bf_rne(a.y) << 16);
    u32 o1 = f2bf_rne(a.z) | ((u32)f2bf_rne(a.w) << 16);
    u32 o2 = f2bf_rne(b.x) | ((u32)f2bf_rne(b.y) << 16);
    u32 o3 = f2bf_rne(b.z) | ((u32)f2bf_rne(b.w) << 16);
    ((uint4*)dst)[i] = make_uint4(o0, o1, o2, o3);
  }
}

// ---------------- W_ih|W_hh -> concat bf16 3-level split ----------------
// w = w1 + w2 + w3 + r, |r| <= 2^-27 |w|  (each split step Sterbenz-exact)
__global__ __launch_bounds__(256) void tobf16x3_gru(
    const float* __restrict__ Wih, const float* __restrict__ Whh,
    ushort* __restrict__ w1, ushort* __restrict__ w2, ushort* __restrict__ w3,
    int n8) {
  int i = blockIdx.x * 256 + threadIdx.x;
  const int stride = gridDim.x * 256;
  const int half = 3072 * HD / 8;
  for (; i < n8; i += stride) {
    const float4* s4 = (i < half) ? ((const float4*)Wih + (size_t)i * 2)
                                  : ((const float4*)Whh + (size_t)(i - half) * 2);
    float v[8];
    float4 a = s4[0], b = s4[1];
    v[0]=a.x; v[1]=a.y; v[2]=a.z; v[3]=a.w; v[4]=b.x; v[5]=b.y; v[6]=b.z; v[7]=b.w;
    ushort p1[8], p2[8], p3[8];
#pragma unroll
    for (int e = 0; e < 8; ++e) {
      p1[e] = f2bf_rne(v[e]);
      float r1 = v[e] - bf2f(p1[e]);
      p2[e] = f2bf_rne(r1);
      float r2 = r1 - bf2f(p2[e]);
      p3[e] = f2bf_rne(r2);
    }
    u32 o1[4], o2[4], o3[4];
#pragma unroll
    for (int e = 0; e < 4; ++e) {
      o1[e] = p1[2*e] | ((u32)p1[2*e+1] << 16);
      o2[e] = p2[2*e] | ((u32)p2[2*e+1] << 16);
      o3[e] = p3[2*e] | ((u32)p3[2*e+1] << 16);
    }
    ((uint4*)w1)[i] = make_uint4(o1[0], o1[1], o1[2], o1[3]);
    ((uint4*)w2)[i] = make_uint4(o2[0], o2[1], o2[2], o2[3]);
    ((uint4*)w3)[i] = make_uint4(o3[0], o3[1], o3[2], o3[3]);
  }
}

// ---------------- fc_in skinny NT GEMM (fp32, one-time) ----------------
__global__ __launch_bounds__(256) void gemm64_nt(
    const float* __restrict__ A, const float* __restrict__ B,
    float* __restrict__ part) {
  __shared__ float4 As4[64 * 33];
  __shared__ float4 Bs4[32 * 33];
  const int tid = threadIdx.x;
  const int n0 = blockIdx.x * 32;
  const float* Brow = B + (size_t)n0 * HD;
  const int ks = blockIdx.y * 256;
  const int tc = tid & 7, trg = tid >> 3;
  float acc[2][4] = {};
  for (int kc = 0; kc < 2; ++kc) {
    const int k0 = ks + kc * 128;
#pragma unroll
    for (int l = 0; l < 8; ++l) {
      int m = tid + l * 256; int row = m >> 5, k4 = m & 31;
      As4[row * 33 + k4] = *(const float4*)(A + (size_t)row * HD + k0 + k4 * 4);
    }
#pragma unroll
    for (int l = 0; l < 4; ++l) {
      int m = tid + l * 256; int row = m >> 5, k4 = m & 31;
      Bs4[row * 33 + k4] = *(const float4*)(Brow + (size_t)row * HD + k0 + k4 * 4);
    }
    __syncthreads();
#pragma unroll
    for (int kq = 0; kq < 32; ++kq) {
      float4 av[2], bv[4];
      av[0] = As4[trg * 33 + kq];
      av[1] = As4[(trg + 32) * 33 + kq];
      bv[0] = Bs4[tc * 33 + kq];
      bv[1] = Bs4[(tc + 8) * 33 + kq];
      bv[2] = Bs4[(tc + 16) * 33 + kq];
      bv[3] = Bs4[(tc + 24) * 33 + kq];
#pragma unroll
      for (int i = 0; i < 2; ++i)
#pragma unroll
        for (int j = 0; j < 4; ++j) {
          acc[i][j] += av[i].x * bv[j].x;
          acc[i][j] += av[i].y * bv[j].y;
          acc[i][j] += av[i].z * bv[j].z;
          acc[i][j] += av[i].w * bv[j].w;
        }
    }
    __syncthreads();
  }
  float* P = part + (size_t)blockIdx.y * BBATCH * HD;
#pragma unroll
  for (int i = 0; i < 2; ++i) {
    int b = trg + 32 * i;
#pragma unroll
    for (int j = 0; j < 4; ++j)
      P[(size_t)b * HD + n0 + tc + 8 * j] = acc[i][j];
  }
}

// ---------------- fc_in combine (+ 3-level split of h0) ----------------
__global__ __launch_bounds__(256) void combine_fcin(
    const float* __restrict__ part, const float* __restrict__ b_fc,
    float* __restrict__ h, ushort* __restrict__ h1, ushort* __restrict__ h2,
    ushort* __restrict__ h3) {
  int idx = blockIdx.x * 256 + threadIdx.x;
  int j = idx & 1023; int b = idx >> 10;
  const size_t S = (size_t)BBATCH * HD;
  const float* p = part + (size_t)b * HD;
  float d = p[j]; d += p[S + j]; d += p[2 * S + j]; d += p[3 * S + j];
  float hv = d + b_fc[j];
  h[idx] = hv;
  ushort a = f2bf_rne(hv);
  float r1 = hv - bf2f(a);
  ushort bb = f2bf_rne(r1);
  float r2 = r1 - bf2f(bb);
  h1[idx] = a; h2[idx] = bb; h3[idx] = f2bf_rne(r2);
}

// ---------------- GRU GEMM: fp32-emulated via bf16 3-split, 6-product MFMA --
// grid (ncols/32, 2 ksplit); 256 thr = 4 waves (2 row-halves x 2 col-halves).
// tile 64 rows x 32 cols; K half = 512 (8 kt of 64).
__global__ __launch_bounds__(256) void gru_gemm(
    const ushort* __restrict__ h1, const ushort* __restrict__ h2,
    const ushort* __restrict__ h3,
    const ushort* __restrict__ W1, const ushort* __restrict__ W2,
    const ushort* __restrict__ W3,
    int colBase, float* __restrict__ g2) {
  __shared__ ushort A1s[64 * 64], A2s[64 * 64], A3s[64 * 64];  // 8 KB each
  __shared__ ushort B1s[32 * 64], B2s[32 * 64], B3s[32 * 64];  // 4 KB each
  const int tid = threadIdx.x;
  const int lane = tid & 63, wid = tid >> 6;
  const int wr = wid >> 1, wc = wid & 1;
  const int n0 = colBase + blockIdx.x * 32;
  const int kb0 = blockIdx.y * 512;
  const ushort* B1g = W1 + (size_t)n0 * HD;
  const ushort* B2g = W2 + (size_t)n0 * HD;
  const ushort* B3g = W3 + (size_t)n0 * HD;
  const int rc = lane >> 3;
  const int gr8 = ((lane & 7) ^ rc) * 8;
  const int l15 = lane & 15;
  const int kseg = (lane >> 4) * 16;

  f32x4 acc[2];
  acc[0] = (f32x4){0.f, 0.f, 0.f, 0.f};
  acc[1] = (f32x4){0.f, 0.f, 0.f, 0.f};

  for (int kt = 0; kt < 8; ++kt) {
    const int k0 = kb0 + kt * 64;
    // 36 chunks (A: 8x3 levels, B: 4x3 levels); wave w issues 9
#pragma unroll
    for (int c = 0; c < 9; ++c) {
      int q = wid * 9 + c;
      const ushort* src; ushort* dst; int cl;
      if (q < 8)       { cl = q;      src = h1 + (size_t)(cl*8+rc) * HD;  dst = A1s + cl*512; }
      else if (q < 16) { cl = q - 8;  src = h2 + (size_t)(cl*8+rc) * HD;  dst = A2s + cl*512; }
      else if (q < 24) { cl = q - 16; src = h3 + (size_t)(cl*8+rc) * HD;  dst = A3s + cl*512; }
      else if (q < 28) { cl = q - 24; src = B1g + (size_t)(cl*8+rc) * HD; dst = B1s + cl*512; }
      else if (q < 32) { cl = q - 28; src = B2g + (size_t)(cl*8+rc) * HD; dst = B2s + cl*512; }
      else             { cl = q - 32; src = B3g + (size_t)(cl*8+rc) * HD; dst = B3s + cl*512; }
      gload16(src + k0 + gr8, dst);
    }
    asm volatile("s_waitcnt vmcnt(0)" ::: "memory");
    __syncthreads();
#pragma unroll
    for (int ks = 0; ks < 2; ++ks) {
      const int kb = ks * 64 + kseg;
      bf16x8 a1[2], a2[2], a3[2], b1, b2, b3;
#pragma unroll
      for (int m = 0; m < 2; ++m) {
        int row = wr * 32 + m * 16 + l15;
        int off = row * 128 + (kb ^ ((row & 7) << 4));
        a1[m] = *(const bf16x8*)((const char*)A1s + off);
        a2[m] = *(const bf16x8*)((const char*)A2s + off);
        a3[m] = *(const bf16x8*)((const char*)A3s + off);
      }
      {
        int row = wc * 16 + l15;
        int off = row * 128 + (kb ^ ((row & 7) << 4));
        b1 = *(const bf16x8*)((const char*)B1s + off);
        b2 = *(const bf16x8*)((const char*)B2s + off);
        b3 = *(const bf16x8*)((const char*)B3s + off);
      }
      // 6 products, smallest-magnitude first; dropped terms <= ~2^-26
#pragma unroll
      for (int m = 0; m < 2; ++m) {
        acc[m] = __builtin_amdgcn_mfma_f32_16x16x32_bf16(a3[m], b1, acc[m], 0, 0, 0);
        acc[m] = __builtin_amdgcn_mfma_f32_16x16x32_bf16(a1[m], b3, acc[m], 0, 0, 0);
        acc[m] = __builtin_amdgcn_mfma_f32_16x16x32_bf16(a2[m], b2, acc[m], 0, 0, 0);
        acc[m] = __builtin_amdgcn_mfma_f32_16x16x32_bf16(a2[m], b1, acc[m], 0, 0, 0);
        acc[m] = __builtin_amdgcn_mfma_f32_16x16x32_bf16(a1[m], b2, acc[m], 0, 0, 0);
        acc[m] = __builtin_amdgcn_mfma_f32_16x16x32_bf16(a1[m], b1, acc[m], 0, 0, 0);
      }
    }
    __syncthreads();
  }
  float* G = g2 + (size_t)blockIdx.y * BBATCH * GATE6;
#pragma unroll
  for (int m = 0; m < 2; ++m)
#pragma unroll
    for (int j = 0; j < 4; ++j) {
      int row = wr * 32 + m * 16 + (lane >> 4) * 4 + j;
      int col = n0 + wc * 16 + l15;
      G[(size_t)row * GATE6 + col] = acc[m][j];
    }
}

// ---------------- GRU gate math (reads 2 K-split partials) ----------------
__global__ __launch_bounds__(256) void gru_gate2(
    const float* __restrict__ g2, const float* __restrict__ b_ih,
    const float* __restrict__ b_hh, float* __restrict__ h,
    float* __restrict__ outs, ushort* __restrict__ outs_bf,
    ushort* __restrict__ h1, ushort* __restrict__ h2, ushort* __restrict__ h3,
    int t, int first) {
  int idx = blockIdx.x * 256 + threadIdx.x;
  int b = idx >> 10, j = idx & 1023;
  const size_t S = (size_t)BBATCH * GATE6;
  const float* p = g2 + (size_t)b * GATE6;
  float gir, giz, gin;
  if (first) {
    gir = b_ih[j]; giz = b_ih[HD + j]; gin = b_ih[2 * HD + j];
  } else {
    gir = p[j]        + p[S + j]        + b_ih[j];
    giz = p[HD + j]   + p[S + HD + j]   + b_ih[HD + j];
    gin = p[2*HD + j] + p[S + 2*HD + j] + b_ih[2 * HD + j];
  }
  float ghr = p[3072 + j]        + p[S + 3072 + j]        + b_hh[j];
  float ghz = p[3072 + HD + j]   + p[S + 3072 + HD + j]   + b_hh[HD + j];
  float ghn = p[3072 + 2*HD + j] + p[S + 3072 + 2*HD + j] + b_hh[2 * HD + j];
  float r = 1.0f / (1.0f + expf(-(gir + ghr)));
  float z = 1.0f / (1.0f + expf(-(giz + ghz)));
  float n = tanhf(gin + r * ghn);
  float hp = h[idx];
  float hn = (1.0f - z) * n + z * hp;
  h[idx] = hn;
  size_t o = ((size_t)t * BBATCH + b) * HD + j;
  outs[o] = hn;
  ushort a = f2bf_rne(hn);
  outs_bf[o] = a;
  float r1 = hn - bf2f(a);
  ushort bb = f2bf_rne(r1);
  float r2 = r1 - bf2f(bb);
  h1[idx] = a; h2[idx] = bb; h3[idx] = f2bf_rne(r2);
}

// ---------------- bf16 MFMA fc_out prefilter, rb-loop inside block ----------
// grid (2 row-halves, 250 col-blocks); each block does 8 row-tiles of 128,
// reusing its W col-slice from L2/L3. 256 thr (4 waves 2x2).
__global__ __launch_bounds__(256) void gemm_out_mfma(
    const ushort* __restrict__ Abf, const ushort* __restrict__ Bbf,
    const float* __restrict__ b_out, u64* __restrict__ keys) {
  __shared__ ushort Asm[128 * 64];
  __shared__ ushort Bsm[128 * 64];
  __shared__ float Cs[32 * 133];
  __shared__ u64 pk[64 * 4];

  const int tid = threadIdx.x;
  const int lane = tid & 63;
  const int wid = tid >> 6;
  const int wr = wid >> 1, wc = wid & 1;
  const int cb = blockIdx.y;
  const int half = blockIdx.x;
  const int n0 = cb * 128;

  const ushort* Bg = Bbf + (size_t)n0 * HD;
  const int rc = lane >> 3;
  const int gr8 = ((lane & 7) ^ rc) * 8;
  const int l15 = lane & 15;
  const int kseg = (lane >> 4) * 16;

  float bo[4];
#pragma unroll
  for (int n = 0; n < 4; ++n) bo[n] = b_out[n0 + wc * 64 + n * 16 + l15];

  for (int rb = 0; rb < 8; ++rb) {
    const int r0 = (half * 8 + rb) * 128;
    const ushort* Ag = Abf + (size_t)r0 * HD;

    f32x4 acc[4][4];
#pragma unroll
    for (int m = 0; m < 4; ++m)
#pragma unroll
      for (int n = 0; n < 4; ++n) acc[m][n] = (f32x4){0.f, 0.f, 0.f, 0.f};

    for (int kt = 0; kt < 16; ++kt) {
      const int k0 = kt * 64;
#pragma unroll
      for (int c = 0; c < 4; ++c) {
        int ch = wid * 4 + c;
        int row = ch * 8 + rc;
        gload16(Ag + (size_t)row * HD + k0 + gr8, Asm + ch * 512);
        gload16(Bg + (size_t)row * HD + k0 + gr8, Bsm + ch * 512);
      }
      asm volatile("s_waitcnt vmcnt(0)" ::: "memory");
      __syncthreads();
#pragma unroll
      for (int ks = 0; ks < 2; ++ks) {
        bf16x8 a[4], b[4];
#pragma unroll
        for (int m = 0; m < 4; ++m) {
          int row = wr * 64 + m * 16 + l15;
          int kb = ks * 64 + kseg;
          int off = row * 128 + (kb ^ ((row & 7) << 4));
          a[m] = *(const bf16x8*)((const char*)Asm + off);
        }
#pragma unroll
        for (int n = 0; n < 4; ++n) {
          int row = wc * 64 + n * 16 + l15;
          int kb = ks * 64 + kseg;
          int off = row * 128 + (kb ^ ((row & 7) << 4));
          b[n] = *(const bf16x8*)((const char*)Bsm + off);
        }
#pragma unroll
        for (int m = 0; m < 4; ++m)
#pragma unroll
          for (int n = 0; n < 4; ++n)
            acc[m][n] = __builtin_amdgcn_mfma_f32_16x16x32_bf16(a[m], b[n], acc[m][n], 0, 0, 0);
      }
      __syncthreads();
    }

    // epilogue: 4 quarters of 32 rows; per row top-4 keys over this 128-col slice
    for (int q = 0; q < 4; ++q) {
      if (wr == (q >> 1)) {
        int mbase = (q & 1) * 2;
#pragma unroll
        for (int mi = 0; mi < 2; ++mi) {
          int m = mbase + mi;
#pragma unroll
          for (int n = 0; n < 4; ++n) {
            int c = wc * 64 + n * 16 + l15;
#pragma unroll
            for (int j = 0; j < 4; ++j) {
              int lr = mi * 16 + (lane >> 4) * 4 + j;
              Cs[lr * 133 + c] = acc[m][n][j] + bo[n];
            }
          }
        }
      }
      __syncthreads();
      if (tid < 64) {
        int rr = tid >> 1, hc = (tid & 1) * 64;
        const float* rp = Cs + rr * 133 + hc;
        u64 t4[4] = {0, 0, 0, 0};
        for (int c = 0; c < 64; ++c) insert4(t4, packkey(rp[c], n0 + hc + c));
        u64* d = pk + tid * 4;
        d[0] = t4[0]; d[1] = t4[1]; d[2] = t4[2]; d[3] = t4[3];
      }
      __syncthreads();
      if (tid < 32) {
        const u64* a4 = pk + tid * 8;
        u64 t4[4] = {a4[0], a4[1], a4[2], a4[3]};
        insert4(t4, a4[4]); insert4(t4, a4[5]); insert4(t4, a4[6]); insert4(t4, a4[7]);
        int grow = r0 + q * 32 + tid;
        u64* kp = keys + ((size_t)grow * NCB + cb) * 4;
        kp[0] = t4[0]; kp[1] = t4[1]; kp[2] = t4[2]; kp[3] = t4[3];
      }
      __syncthreads();
    }
  }
}

// ---------------- per-row: top-16 -> fp32 rescore -> top-8 -> sample ------
__global__ __launch_bounds__(256) void merge_sample2(
    const u64* __restrict__ keys, const float* __restrict__ outs,
    const float* __restrict__ W_out, const float* __restrict__ b_out,
    int* __restrict__ out) {
  const int r = blockIdx.x, tid = threadIdx.x;
  const int lane = tid & 63, wid = tid >> 6;
  __shared__ u64 K[1000];
  __shared__ u64 wmax[4];
  __shared__ u64 topw[NCAND];
  __shared__ float candv[NCAND];
  __shared__ float row_f[1024];
  for (int i = tid; i < 1000; i += 256) K[i] = keys[(size_t)r * 1000 + i];
  for (int i = tid; i < 1024; i += 256) row_f[i] = outs[(size_t)r * 1024 + i];
  __syncthreads();
  // NCAND rounds of shfl-based argmax-and-kill
  for (int it = 0; it < NCAND; ++it) {
    u64 b = 0;
#pragma unroll
    for (int l = 0; l < 4; ++l) {
      int i = tid + l * 256;
      if (i < 1000) { u64 v = K[i]; b = (v > b) ? v : b; }
    }
#pragma unroll
    for (int o = 32; o; o >>= 1) {
      u64 x = __shfl_xor(b, o);
      if (x > b) b = x;
    }
    if (lane == 0) wmax[wid] = b;
    __syncthreads();
    u64 w = wmax[0];
    if (wmax[1] > w) w = wmax[1];
    if (wmax[2] > w) w = wmax[2];
    if (wmax[3] > w) w = wmax[3];
    if (tid == 0) topw[it] = w;
#pragma unroll
    for (int l = 0; l < 4; ++l) {
      int i = tid + l * 256;
      if (i < 1000 && K[i] == w) K[i] = 0;
    }
    __syncthreads();
  }
  // exact fp32 rescore: 16 cands x 16 threads
  {
    int c = tid >> 4, l16 = tid & 15;
    int vidx = (int)(~(u32)(topw[c] & 0xffffffffu));
    const float* wrow = W_out + (size_t)vidx * HD;
    float s = 0.f;
    for (int e = l16; e < 1024; e += 16) s += row_f[e] * wrow[e];
#pragma unroll
    for (int o = 8; o; o >>= 1) s += __shfl_xor(s, o, 16);
    if (l16 == 0) candv[c] = s + b_out[vidx];
  }
  __syncthreads();
  if (tid == 0) {
    float v[NCAND]; int vi[NCAND];
#pragma unroll
    for (int q = 0; q < NCAND; ++q) {
      v[q] = candv[q];
      vi[q] = (int)(~(u32)(topw[q] & 0xffffffffu));
    }
    for (int a = 0; a < 8; ++a)
      for (int b2 = a + 1; b2 < NCAND; ++b2) {
        bool sw = (v[b2] > v[a]) || (v[b2] == v[a] && vi[b2] < vi[a]);
        if (sw) {
          float tf = v[a]; v[a] = v[b2]; v[b2] = tf;
          int ti = vi[a]; vi[a] = vi[b2]; vi[b2] = ti;
        }
      }
    const float M = v[0];
    const float TINY = 1.17549435e-38f;
    float best = -3.4e38f; int bi = 0;
    for (int k = 0; k < 8; ++k) {
      float lp = v[k] - M;   // log_softmax shift cancels in gumbel argmax
      u32 bits = jax_random_bits((u32)(r * 8 + k));
      float f = __uint_as_float((bits >> 9) | 0x3f800000u) - 1.0f;
      float u = f * (1.0f - TINY) + TINY;
      u = fmaxf(TINY, u);
      float g = -logf(-logf(u));
      float s = g + lp;
      if (s > best) { best = s; bi = k; }
    }
    int t = r >> 6, b = r & 63;
    out[b * TSTEP + t] = vi[bi];
  }
}

extern "C" void kernel_launch(void* const* d_in, const int* in_sizes, int n_in,
                              void* d_out, int out_size, void* d_ws, size_t ws_size,
                              hipStream_t stream) {
  (void)in_sizes; (void)n_in; (void)out_size; (void)ws_size;
  const float* vectors = (const float*)d_in[0];
  const float* W_fc_in = (const float*)d_in[1];
  const float* b_fc_in = (const float*)d_in[2];
  const float* W_ih    = (const float*)d_in[3];
  const float* W_hh    = (const float*)d_in[4];
  const float* b_ih    = (const float*)d_in[5];
  const float* b_hh    = (const float*)d_in[6];
  const float* W_out   = (const float*)d_in[7];
  const float* b_out   = (const float*)d_in[8];
  int* out = (int*)d_out;

  char* w = (char*)d_ws;
  float* h = (float*)w;          w += (size_t)BBATCH * HD * 4;        // 256 KB
  float* outs = (float*)w;       w += (size_t)NROWS * HD * 4;         // 8 MB
  ushort* outs_bf = (ushort*)w;  w += (size_t)NROWS * HD * 2;         // 4 MB
  ushort* Wbf = (ushort*)w;      w += (size_t)VOCAB * HD * 2;         // 65.5 MB
  // X region: Wg 3-level splits live during GRU; keys (16 MB) aliases it
  // afterwards (prefilter runs after the last gru_gemm).
  char* X = w;                   w += (size_t)3 * GATE6 * HD * 2;     // 37.75 MB
  ushort* Wg1 = (ushort*)X;
  ushort* Wg2 = Wg1 + (size_t)GATE6 * HD;
  ushort* Wg3 = Wg2 + (size_t)GATE6 * HD;
  u64* keys = (u64*)X;                                               // 16 MB alias
  ushort* h1 = (ushort*)w;       w += (size_t)BBATCH * HD * 2;        // 128 KB
  ushort* h2 = (ushort*)w;       w += (size_t)BBATCH * HD * 2;        // 128 KB
  ushort* h3 = (ushort*)w;       w += (size_t)BBATCH * HD * 2;        // 128 KB
  float* part = (float*)w;       // fc_in partials: 4*64*1024 fp32 = 1 MB
  float* g2   = (float*)w;       // GRU partials:   2*64*6144 fp32 = 3.1 MB

  // one-time weight conversions
  tobf16<<<4096, 256, 0, stream>>>(W_out, Wbf, VOCAB * HD / 8);
  tobf16x3_gru<<<1024, 256, 0, stream>>>(W_ih, W_hh, Wg1, Wg2, Wg3, GATE6 * HD / 8);

  // fc_in: h0 = vectors @ W_fc_in^T + b_fc_in  (fp32, split-K=4)
  gemm64_nt<<<dim3(32, 4), 256, 0, stream>>>(vectors, W_fc_in, part);
  combine_fcin<<<256, 256, 0, stream>>>(part, b_fc_in, h, h1, h2, h3);

  // 32 GRU steps on matrix cores (bf16 3-split, 6 products -> fp32-noise class)
  for (int t = 0; t < TSTEP; ++t) {
    if (t == 0)
      gru_gemm<<<dim3(96, 2), 256, 0, stream>>>(h1, h2, h3, Wg1, Wg2, Wg3, 3072, g2);
    else
      gru_gemm<<<dim3(192, 2), 256, 0, stream>>>(h1, h2, h3, Wg1, Wg2, Wg3, 0, g2);
    gru_gate2<<<256, 256, 0, stream>>>(g2, b_ih, b_hh, h, outs, outs_bf,
                                       h1, h2, h3, t, t == 0 ? 1 : 0);
  }

  // bf16 MFMA prefilter over the vocab (W slice reused across 8 row-tiles)
  gemm_out_mfma<<<dim3(2, NCB), 256, 0, stream>>>(outs_bf, Wbf, b_out, keys);

  // exact fp32 rescore of top-16 + Threefry/Gumbel sampling
  merge_sample2<<<NROWS, 256, 0, stream>>>(keys, outs, W_out, b_out, out);
}